// Round 1
// baseline (7300.838 us; speedup 1.0000x reference)
//
#include <hip/hip_runtime.h>
#include <math.h>

// ArcFace margin loss: B=1024 x E=512 embeddings vs C=200000 x E weight.
// loss = mean_b [ LSE_c(64*clip(cos_bc)) - 64*cos(acos(clip(cos_b,lbl)) + 0.5) ]
// Strategy: fused GEMM + online per-chunk (max, sumexp) partials; never
// materialize the 1024x200000 logits matrix.

#define S_SCALE 64.0f
#define MARGIN2 0.5f
#define EPSS 1e-7f

#define BATCH 1024
#define EMB 512
#define NCLS 200000

#define BM 128
#define BN 128
#define BKT 16
#define NCHUNKS ((NCLS + BN - 1) / BN) // 1563

// ---- workspace layout (float offsets) ----
#define OFF_NE 0
#define LEN_NE (BATCH * EMB)                 // 524288
#define OFF_WINV (OFF_NE + LEN_NE)
#define LEN_WINV 200192                      // 200000 padded
#define OFF_PM (OFF_WINV + LEN_WINV)
#define LEN_P (BATCH * NCHUNKS)              // 1600512
#define OFF_PL (OFF_PM + LEN_P)
#define OFF_TSV (OFF_PL + LEN_P)
#define OFF_RL (OFF_TSV + BATCH)
// total ~3.93M floats = ~15.7 MB

// Kernel 1: L2-normalize embedding rows. One block per row.
__global__ void norm_emb_kernel(const float* __restrict__ e, float* __restrict__ ne) {
    int r = blockIdx.x;
    int t = threadIdx.x;
    float v0 = e[r * EMB + t];
    float v1 = e[r * EMB + t + 256];
    __shared__ float red[256];
    red[t] = v0 * v0 + v1 * v1;
    __syncthreads();
    for (int o = 128; o > 0; o >>= 1) {
        if (t < o) red[t] += red[t + o];
        __syncthreads();
    }
    float inv = 1.0f / fmaxf(sqrtf(red[0]), 1e-12f);
    ne[r * EMB + t] = v0 * inv;
    ne[r * EMB + t + 256] = v1 * inv;
}

// Kernel 2: per-class inverse norms. One wave (64 lanes) per class row.
__global__ void winv_kernel(const float* __restrict__ w, float* __restrict__ winv) {
    int tid = threadIdx.x;
    int wv = tid >> 6, lane = tid & 63;
    int row = blockIdx.x * 4 + wv; // grid = 50000 -> exactly 200000 rows
    const float* wr = w + (size_t)row * EMB;
    float ss = 0.f;
#pragma unroll
    for (int q = 0; q < 8; ++q) {
        float v = wr[lane + 64 * q];
        ss += v * v;
    }
#pragma unroll
    for (int m = 32; m >= 1; m >>= 1) ss += __shfl_xor(ss, m);
    if (lane == 0) winv[row] = 1.0f / fmaxf(sqrtf(ss), 1e-12f);
}

// Kernel 3: tiled fp32 GEMM (dot(ne_b, w_c)) + fused arcface epilogue.
// Block = 256 threads = 16x16, each thread owns an 8x8 microtile.
__global__ __launch_bounds__(256) void gemm_lse_kernel(
    const float* __restrict__ ne, const float* __restrict__ w,
    const float* __restrict__ winv, const int* __restrict__ labels,
    float* __restrict__ pm, float* __restrict__ pl, float* __restrict__ tsv) {
    __shared__ float As[BKT][BM];
    __shared__ float Bs[BKT][BN];
    int tid = threadIdx.x;
    int tx = tid & 15, ty = tid >> 4;
    int rowBase = blockIdx.y * BM;
    int colBase = blockIdx.x * BN;

    float acc[8][8];
#pragma unroll
    for (int i = 0; i < 8; i++)
#pragma unroll
        for (int j = 0; j < 8; j++) acc[i][j] = 0.f;

    for (int kt = 0; kt < EMB; kt += BKT) {
        // stage A tile: 128 rows x 16 k, float4 along k
#pragma unroll
        for (int p = 0; p < 2; ++p) {
            int f = tid + p * 256;
            int row = f >> 2, kq = f & 3;
            const float4 v = *(const float4*)(ne + (size_t)(rowBase + row) * EMB + kt + kq * 4);
            As[kq * 4 + 0][row] = v.x;
            As[kq * 4 + 1][row] = v.y;
            As[kq * 4 + 2][row] = v.z;
            As[kq * 4 + 3][row] = v.w;
        }
        // stage B tile: 128 classes x 16 k (bounds-checked)
#pragma unroll
        for (int p = 0; p < 2; ++p) {
            int f = tid + p * 256;
            int row = f >> 2, kq = f & 3;
            int cls = colBase + row;
            float4 v = make_float4(0.f, 0.f, 0.f, 0.f);
            if (cls < NCLS) v = *(const float4*)(w + (size_t)cls * EMB + kt + kq * 4);
            Bs[kq * 4 + 0][row] = v.x;
            Bs[kq * 4 + 1][row] = v.y;
            Bs[kq * 4 + 2][row] = v.z;
            Bs[kq * 4 + 3][row] = v.w;
        }
        __syncthreads();
#pragma unroll
        for (int kk = 0; kk < BKT; ++kk) {
            float4 a0 = *(const float4*)&As[kk][ty * 8];
            float4 a1 = *(const float4*)&As[kk][ty * 8 + 4];
            float4 b0 = *(const float4*)&Bs[kk][tx * 8];
            float4 b1 = *(const float4*)&Bs[kk][tx * 8 + 4];
            float a[8] = {a0.x, a0.y, a0.z, a0.w, a1.x, a1.y, a1.z, a1.w};
            float b[8] = {b0.x, b0.y, b0.z, b0.w, b1.x, b1.y, b1.z, b1.w};
#pragma unroll
            for (int i = 0; i < 8; i++)
#pragma unroll
                for (int j = 0; j < 8; j++) acc[i][j] = fmaf(a[i], b[j], acc[i][j]);
        }
        __syncthreads();
    }

    // epilogue: normalize-by-winv, clamp, arcface target, x64, row (max,sumexp)
    float wvv[8];
    int gcv[8];
#pragma unroll
    for (int j = 0; j < 8; j++) {
        int gc = colBase + tx * 8 + j;
        gcv[j] = gc;
        wvv[j] = (gc < NCLS) ? winv[gc] : 0.f;
    }
#pragma unroll
    for (int i = 0; i < 8; i++) {
        int grow = rowBase + ty * 8 + i;
        int lbl = labels[grow];
        float vals[8];
        float rmax = -1e30f;
#pragma unroll
        for (int j = 0; j < 8; j++) {
            float v;
            if (gcv[j] < NCLS) {
                v = acc[i][j] * wvv[j];
                v = fminf(fmaxf(v, -1.f), 1.f);
                if (gcv[j] == lbl) {
                    float tt = fminf(fmaxf(v, -1.f + EPSS), 1.f - EPSS);
                    v = cosf(acosf(tt) + MARGIN2);
                    tsv[grow] = v * S_SCALE; // unique writer across grid
                }
                v *= S_SCALE;
            } else {
                v = -1e30f; // exp(-1e30 - m) == 0
            }
            vals[j] = v;
            rmax = fmaxf(rmax, v);
        }
        // reduce across the 16 lanes (tx) sharing this row
#pragma unroll
        for (int m = 1; m < 16; m <<= 1) rmax = fmaxf(rmax, __shfl_xor(rmax, m));
        float s = 0.f;
#pragma unroll
        for (int j = 0; j < 8; j++) s += expf(vals[j] - rmax);
#pragma unroll
        for (int m = 1; m < 16; m <<= 1) s += __shfl_xor(s, m);
        if (tx == 0) {
            pm[(size_t)grow * NCHUNKS + blockIdx.x] = rmax;
            pl[(size_t)grow * NCHUNKS + blockIdx.x] = s;
        }
    }
}

// Kernel 4: per-row reduction over 1563 chunk partials -> row loss.
__global__ void chunk_reduce_kernel(const float* __restrict__ pm, const float* __restrict__ pl,
                                    const float* __restrict__ tsv, float* __restrict__ rowloss) {
    int r = blockIdx.x, t = threadIdx.x;
    const float* m = pm + (size_t)r * NCHUNKS;
    const float* l = pl + (size_t)r * NCHUNKS;
    __shared__ float red[256];
    float lmax = -1e30f;
    for (int i = t; i < NCHUNKS; i += 256) lmax = fmaxf(lmax, m[i]);
    red[t] = lmax;
    __syncthreads();
    for (int o = 128; o > 0; o >>= 1) {
        if (t < o) red[t] = fmaxf(red[t], red[t + o]);
        __syncthreads();
    }
    float M = red[0];
    __syncthreads();
    float s = 0.f;
    for (int i = t; i < NCHUNKS; i += 256) s += l[i] * expf(m[i] - M);
    red[t] = s;
    __syncthreads();
    for (int o = 128; o > 0; o >>= 1) {
        if (t < o) red[t] += red[t + o];
        __syncthreads();
    }
    if (t == 0) rowloss[r] = M + logf(red[0]) - tsv[r];
}

// Kernel 5: mean over 1024 rows -> scalar loss.
__global__ void final_kernel(const float* __restrict__ rowloss, float* __restrict__ out) {
    int t = threadIdx.x;
    float s = 0.f;
    for (int i = t; i < BATCH; i += 256) s += rowloss[i];
    __shared__ float red[256];
    red[t] = s;
    __syncthreads();
    for (int o = 128; o > 0; o >>= 1) {
        if (t < o) red[t] += red[t + o];
        __syncthreads();
    }
    if (t == 0) out[0] = red[0] / (float)BATCH;
}

extern "C" void kernel_launch(void* const* d_in, const int* in_sizes, int n_in,
                              void* d_out, int out_size, void* d_ws, size_t ws_size,
                              hipStream_t stream) {
    const float* emb = (const float*)d_in[0];
    const float* w = (const float*)d_in[1];
    const int* labels = (const int*)d_in[2];
    float* ws = (float*)d_ws;
    float* ne = ws + OFF_NE;
    float* winv = ws + OFF_WINV;
    float* pm = ws + OFF_PM;
    float* pl = ws + OFF_PL;
    float* tsv = ws + OFF_TSV;
    float* rl = ws + OFF_RL;

    norm_emb_kernel<<<BATCH, 256, 0, stream>>>(emb, ne);
    winv_kernel<<<NCLS / 4, 256, 0, stream>>>(w, winv);
    dim3 grid(NCHUNKS, BATCH / BM);
    gemm_lse_kernel<<<grid, 256, 0, stream>>>(ne, w, winv, labels, pm, pl, tsv);
    chunk_reduce_kernel<<<BATCH, 256, 0, stream>>>(pm, pl, tsv, rl);
    final_kernel<<<1, 256, 0, stream>>>(rl, (float*)d_out);
}

// Round 2
// 1073.646 us; speedup vs baseline: 6.8000x; 6.8000x over previous
//
#include <hip/hip_runtime.h>
#include <math.h>

// ArcFace margin loss: B=1024 x E=512 embeddings vs C=200000 x E weight.
// Round 2: bf16 MFMA GEMM core (16x16x32), fp32 accumulate, fused LSE epilogue.

#define S_SCALE 64.0f
#define MARGIN2 0.5f
#define EPSS 1e-7f

#define BATCH 1024
#define EMB 512
#define NCLS 200000

#define BM 256
#define BN 128
#define BK 32
#define NCHUNKS ((NCLS + BN - 1) / BN) // 1563
#define LDSTR 40  // LDS row stride in bf16 (80 B: 16B-aligned, 2-way-conflict only)

typedef __bf16 bf16x8 __attribute__((ext_vector_type(8)));
typedef float floatx4 __attribute__((ext_vector_type(4)));

// ---- workspace layout (float offsets) ----
#define OFF_NEBF 0
#define LEN_NEBF (BATCH * EMB / 2)           // 1024x512 ushort = 262144 floats
#define OFF_WINV (OFF_NEBF + LEN_NEBF)
#define LEN_WINV 200192
#define OFF_PM (OFF_WINV + LEN_WINV)
#define LEN_P (BATCH * NCHUNKS)              // 1600512
#define OFF_PL (OFF_PM + LEN_P)
#define OFF_TSV (OFF_PL + LEN_P)
#define OFF_RL (OFF_TSV + BATCH)
// total ~3.67M floats ~= 14.7 MB

__device__ inline ushort f2bf(float f) {
    unsigned u = __float_as_uint(f);
    unsigned r = (u + 0x7FFFu + ((u >> 16) & 1u)) >> 16; // RNE
    return (ushort)r;
}

// Kernel 1: L2-normalize embedding rows -> bf16. One block per row.
__global__ void norm_emb_kernel(const float* __restrict__ e, ushort* __restrict__ nebf) {
    int r = blockIdx.x;
    int t = threadIdx.x;
    float v0 = e[r * EMB + t];
    float v1 = e[r * EMB + t + 256];
    __shared__ float red[256];
    red[t] = v0 * v0 + v1 * v1;
    __syncthreads();
    for (int o = 128; o > 0; o >>= 1) {
        if (t < o) red[t] += red[t + o];
        __syncthreads();
    }
    float inv = 1.0f / fmaxf(sqrtf(red[0]), 1e-12f);
    nebf[r * EMB + t] = f2bf(v0 * inv);
    nebf[r * EMB + t + 256] = f2bf(v1 * inv);
}

// Kernel 2: per-class inverse norms. One wave per class row.
__global__ void winv_kernel(const float* __restrict__ w, float* __restrict__ winv) {
    int tid = threadIdx.x;
    int wv = tid >> 6, lane = tid & 63;
    int row = blockIdx.x * 4 + wv;
    const float* wr = w + (size_t)row * EMB;
    float ss = 0.f;
#pragma unroll
    for (int q = 0; q < 8; ++q) {
        float v = wr[lane + 64 * q];
        ss += v * v;
    }
#pragma unroll
    for (int m = 32; m >= 1; m >>= 1) ss += __shfl_xor(ss, m);
    if (lane == 0) winv[row] = 1.0f / fmaxf(sqrtf(ss), 1e-12f);
}

// Kernel 3: bf16 MFMA GEMM + fused arcface/LSE epilogue.
// Block = 512 threads = 8 waves (wave_m 0..3, wave_n 0..1), each wave 64x64.
// grid = (4 row-groups [fast], 1563 class chunks [slow]) for W L2/L3 sharing.
__global__ __launch_bounds__(512) void gemm_lse_kernel(
    const ushort* __restrict__ nebf, const float* __restrict__ w,
    const float* __restrict__ winv, const int* __restrict__ labels,
    float* __restrict__ pm, float* __restrict__ pl, float* __restrict__ tsv) {
    __shared__ ushort Als[BM * LDSTR];  // 20480 B
    __shared__ ushort Bls[BN * LDSTR];  // 10240 B
    __shared__ float pmax[2][BM];
    __shared__ float psum[2][BM];

    const int tid = threadIdx.x;
    const int rowBase = blockIdx.x * BM;
    const int colBase = blockIdx.y * BN;
    const int lane = tid & 63, wv = tid >> 6;
    const int wm = wv & 3, wn = wv >> 1 & 0; // placeholder (computed below)
    (void)wm; (void)wn;
    const int wave_m = wv & 3, wave_n = wv >> 2;
    const int lr = lane & 15, quad = lane >> 4;

    // staging indices
    const int arow = tid >> 1, ahalf = tid & 1;          // A: 256 rows x 2 halves
    const int bcol = tid >> 2, bq = tid & 3;             // B: 128 cols x 4 quarters
    const int bcls = colBase + bcol;
    const bool bvalid = bcls < NCLS;

    floatx4 acc[4][4];
#pragma unroll
    for (int i = 0; i < 4; i++)
#pragma unroll
        for (int j = 0; j < 4; j++) acc[i][j] = (floatx4){0.f, 0.f, 0.f, 0.f};

    for (int kt = 0; kt < EMB; kt += BK) {
        // stage A (bf16 copy): 32 B per thread
        {
            const ushort* src = nebf + (size_t)(rowBase + arow) * EMB + kt + ahalf * 16;
            uint4 v0 = *(const uint4*)(src);
            uint4 v1 = *(const uint4*)(src + 8);
            ushort* dst = &Als[arow * LDSTR + ahalf * 16];
            *(uint4*)(dst) = v0;
            *(uint4*)(dst + 8) = v1;
        }
        // stage B (fp32 -> bf16): 8 floats per thread
        {
            float4 v0 = make_float4(0.f, 0.f, 0.f, 0.f);
            float4 v1 = make_float4(0.f, 0.f, 0.f, 0.f);
            if (bvalid) {
                const float* src = w + (size_t)bcls * EMB + kt + bq * 8;
                v0 = *(const float4*)(src);
                v1 = *(const float4*)(src + 4);
            }
            union { ushort us[8]; uint4 v; } pk;
            pk.us[0] = f2bf(v0.x); pk.us[1] = f2bf(v0.y);
            pk.us[2] = f2bf(v0.z); pk.us[3] = f2bf(v0.w);
            pk.us[4] = f2bf(v1.x); pk.us[5] = f2bf(v1.y);
            pk.us[6] = f2bf(v1.z); pk.us[7] = f2bf(v1.w);
            *(uint4*)&Bls[bcol * LDSTR + bq * 8] = pk.v;
        }
        __syncthreads();

        bf16x8 af[4], bfr[4];
#pragma unroll
        for (int i = 0; i < 4; i++)
            af[i] = *(const bf16x8*)&Als[(wave_m * 64 + i * 16 + lr) * LDSTR + quad * 8];
#pragma unroll
        for (int j = 0; j < 4; j++)
            bfr[j] = *(const bf16x8*)&Bls[(wave_n * 64 + j * 16 + lr) * LDSTR + quad * 8];
#pragma unroll
        for (int i = 0; i < 4; i++)
#pragma unroll
            for (int j = 0; j < 4; j++)
                acc[i][j] = __builtin_amdgcn_mfma_f32_16x16x32_bf16(af[i], bfr[j], acc[i][j], 0, 0, 0);
        __syncthreads();
    }

    // ---- epilogue ----
    // C/D layout: col = lr, row(within 16-tile) = quad*4 + reg.
#pragma unroll
    for (int i = 0; i < 4; i++) {
#pragma unroll
        for (int r = 0; r < 4; r++) {
            int rowloc = wave_m * 64 + i * 16 + quad * 4 + r;
            int grow = rowBase + rowloc;
            int lbl = labels[grow];
            float vals[4];
            float vmax = -1e30f;
#pragma unroll
            for (int j = 0; j < 4; j++) {
                int gc = colBase + wave_n * 64 + j * 16 + lr;
                float v;
                if (gc < NCLS) {
                    v = acc[i][j][r] * winv[gc];
                    v = fminf(fmaxf(v, -1.f), 1.f);
                    if (gc == lbl) {
                        float tt = fminf(fmaxf(v, -1.f + EPSS), 1.f - EPSS);
                        v = __cosf(acosf(tt) + MARGIN2);
                        tsv[grow] = v * S_SCALE; // unique writer across grid
                    }
                    v *= S_SCALE;
                } else {
                    v = -1e30f;
                }
                vals[j] = v;
                vmax = fmaxf(vmax, v);
            }
#pragma unroll
            for (int m = 1; m < 16; m <<= 1) vmax = fmaxf(vmax, __shfl_xor(vmax, m));
            float s = 0.f;
#pragma unroll
            for (int j = 0; j < 4; j++) s += expf(vals[j] - vmax);
#pragma unroll
            for (int m = 1; m < 16; m <<= 1) s += __shfl_xor(s, m);
            if (lr == 0) {
                pmax[wave_n][rowloc] = vmax;
                psum[wave_n][rowloc] = s;
            }
        }
    }
    __syncthreads();
    // combine the two wave_n halves, write per-(row, chunk) partials
    if (tid < BM) {
        float m0 = pmax[0][tid], m1 = pmax[1][tid];
        float M = fmaxf(m0, m1);
        float l = psum[0][tid] * expf(m0 - M) + psum[1][tid] * expf(m1 - M);
        size_t grow = rowBase + tid;
        pm[grow * NCHUNKS + blockIdx.y] = M;
        pl[grow * NCHUNKS + blockIdx.y] = l;
    }
}

// Kernel 4: per-row reduction over chunk partials -> row loss.
__global__ void chunk_reduce_kernel(const float* __restrict__ pm, const float* __restrict__ pl,
                                    const float* __restrict__ tsv, float* __restrict__ rowloss) {
    int r = blockIdx.x, t = threadIdx.x;
    const float* m = pm + (size_t)r * NCHUNKS;
    const float* l = pl + (size_t)r * NCHUNKS;
    __shared__ float red[256];
    float lmax = -1e30f;
    for (int i = t; i < NCHUNKS; i += 256) lmax = fmaxf(lmax, m[i]);
    red[t] = lmax;
    __syncthreads();
    for (int o = 128; o > 0; o >>= 1) {
        if (t < o) red[t] = fmaxf(red[t], red[t + o]);
        __syncthreads();
    }
    float M = red[0];
    __syncthreads();
    float s = 0.f;
    for (int i = t; i < NCHUNKS; i += 256) s += l[i] * expf(m[i] - M);
    red[t] = s;
    __syncthreads();
    for (int o = 128; o > 0; o >>= 1) {
        if (t < o) red[t] += red[t + o];
        __syncthreads();
    }
    if (t == 0) rowloss[r] = M + logf(red[0]) - tsv[r];
}

// Kernel 5: mean over rows -> scalar loss.
__global__ void final_kernel(const float* __restrict__ rowloss, float* __restrict__ out) {
    int t = threadIdx.x;
    float s = 0.f;
    for (int i = t; i < BATCH; i += 256) s += rowloss[i];
    __shared__ float red[256];
    red[t] = s;
    __syncthreads();
    for (int o = 128; o > 0; o >>= 1) {
        if (t < o) red[t] += red[t + o];
        __syncthreads();
    }
    if (t == 0) out[0] = red[0] / (float)BATCH;
}

extern "C" void kernel_launch(void* const* d_in, const int* in_sizes, int n_in,
                              void* d_out, int out_size, void* d_ws, size_t ws_size,
                              hipStream_t stream) {
    const float* emb = (const float*)d_in[0];
    const float* w = (const float*)d_in[1];
    const int* labels = (const int*)d_in[2];
    float* ws = (float*)d_ws;
    ushort* nebf = (ushort*)(ws + OFF_NEBF);
    float* winv = ws + OFF_WINV;
    float* pm = ws + OFF_PM;
    float* pl = ws + OFF_PL;
    float* tsv = ws + OFF_TSV;
    float* rl = ws + OFF_RL;

    norm_emb_kernel<<<BATCH, 256, 0, stream>>>(emb, nebf);
    winv_kernel<<<NCLS / 4, 256, 0, stream>>>(w, winv);
    dim3 grid(BATCH / BM, NCHUNKS); // x = row-group (fast) for W reuse in L2/L3
    gemm_lse_kernel<<<grid, 512, 0, stream>>>(nebf, w, winv, labels, pm, pl, tsv);
    chunk_reduce_kernel<<<BATCH, 256, 0, stream>>>(pm, pl, tsv, rl);
    final_kernel<<<1, 256, 0, stream>>>(rl, (float*)d_out);
}

// Round 3
// 955.726 us; speedup vs baseline: 7.6390x; 1.1234x over previous
//
#include <hip/hip_runtime.h>
#include <math.h>

// ArcFace margin loss: B=1024 x E=512 embeddings vs C=200000 x E weight.
// Round 3: pre-normalized bf16 W (converted once, fused with norm pass),
// fixed-max (=64) online softmax epilogue. Fallback path (template) converts
// W in-kernel if ws_size is too small for the 205 MB bf16 W copy.

#define S_SCALE 64.0f
#define MARGIN2 0.5f
#define EPSS 1e-7f

#define BATCH 1024
#define EMB 512
#define NCLS 200000

#define BM 256
#define BN 128
#define BK 32
#define NCHUNKS ((NCLS + BN - 1) / BN) // 1563
#define NCLS_PAD (NCHUNKS * BN)        // 200064
#define LDSTR 40  // LDS row stride in bf16 (80 B: 16B-aligned, 2-way-conflict only)

typedef __bf16 bf16x8 __attribute__((ext_vector_type(8)));
typedef float floatx4 __attribute__((ext_vector_type(4)));

// ---- workspace layout (float offsets) ----
#define OFF_NEBF 0
#define LEN_NEBF (BATCH * EMB / 2)           // 1024x512 ushort = 262144 floats
#define OFF_WINV (OFF_NEBF + LEN_NEBF)       // fallback path only
#define LEN_WINV 200192
#define OFF_PL (OFF_WINV + LEN_WINV)
#define LEN_P (BATCH * NCHUNKS)              // 1600512
#define OFF_TSV (OFF_PL + LEN_P)
#define OFF_RL (OFF_TSV + BATCH)
#define OFF_WBF (OFF_RL + BATCH)             // 2064896 floats so far (~8.3 MB)
#define LEN_WBF ((size_t)NCLS_PAD * EMB / 2) // 51.2M floats (~205 MB)
#define NEED_BYTES (((size_t)OFF_WBF + LEN_WBF) * 4)

__device__ inline ushort f2bf(float f) {
    unsigned u = __float_as_uint(f);
    unsigned r = (u + 0x7FFFu + ((u >> 16) & 1u)) >> 16; // RNE
    return (ushort)r;
}

// Kernel 1: L2-normalize embedding rows -> bf16. One block per row.
__global__ void norm_emb_kernel(const float* __restrict__ e, ushort* __restrict__ nebf) {
    int r = blockIdx.x;
    int t = threadIdx.x;
    float v0 = e[r * EMB + t];
    float v1 = e[r * EMB + t + 256];
    __shared__ float red[256];
    red[t] = v0 * v0 + v1 * v1;
    __syncthreads();
    for (int o = 128; o > 0; o >>= 1) {
        if (t < o) red[t] += red[t + o];
        __syncthreads();
    }
    float inv = 1.0f / fmaxf(sqrtf(red[0]), 1e-12f);
    nebf[r * EMB + t] = f2bf(v0 * inv);
    nebf[r * EMB + t + 256] = f2bf(v1 * inv);
}

// Kernel 2a (PRE path): per-class normalize + fp32->bf16 convert, one wave/row.
__global__ void norm_w_kernel(const float* __restrict__ w, ushort* __restrict__ wbf) {
    int tid = threadIdx.x;
    int wv = tid >> 6, lane = tid & 63;
    int row = blockIdx.x * 4 + wv; // grid = 50000 -> exactly 200000 rows
    const float* wr = w + (size_t)row * EMB;
    float4 v0 = *(const float4*)(wr + lane * 4);
    float4 v1 = *(const float4*)(wr + lane * 4 + 256);
    float ss = v0.x * v0.x + v0.y * v0.y + v0.z * v0.z + v0.w * v0.w
             + v1.x * v1.x + v1.y * v1.y + v1.z * v1.z + v1.w * v1.w;
#pragma unroll
    for (int m = 32; m >= 1; m >>= 1) ss += __shfl_xor(ss, m);
    float inv = 1.0f / fmaxf(sqrtf(ss), 1e-12f);
    ushort* dst = wbf + (size_t)row * EMB;
    ushort4 p0, p1;
    p0.x = f2bf(v0.x * inv); p0.y = f2bf(v0.y * inv);
    p0.z = f2bf(v0.z * inv); p0.w = f2bf(v0.w * inv);
    p1.x = f2bf(v1.x * inv); p1.y = f2bf(v1.y * inv);
    p1.z = f2bf(v1.z * inv); p1.w = f2bf(v1.w * inv);
    *(ushort4*)(dst + lane * 4) = p0;
    *(ushort4*)(dst + lane * 4 + 256) = p1;
}

// Kernel 2b (fallback): per-class inverse norms only.
__global__ void winv_kernel(const float* __restrict__ w, float* __restrict__ winv) {
    int tid = threadIdx.x;
    int wv = tid >> 6, lane = tid & 63;
    int row = blockIdx.x * 4 + wv;
    const float* wr = w + (size_t)row * EMB;
    float ss = 0.f;
#pragma unroll
    for (int q = 0; q < 8; ++q) {
        float v = wr[lane + 64 * q];
        ss += v * v;
    }
#pragma unroll
    for (int m = 32; m >= 1; m >>= 1) ss += __shfl_xor(ss, m);
    if (lane == 0) winv[row] = 1.0f / fmaxf(sqrtf(ss), 1e-12f);
}

// Kernel 3: bf16 MFMA GEMM + fused arcface epilogue with fixed max = 64.
// Block = 512 threads = 8 waves (wave_m 0..3, wave_n 0..1), each wave 64x64.
template <bool PRE>
__global__ __launch_bounds__(512) void gemm_lse_kernel(
    const ushort* __restrict__ nebf, const ushort* __restrict__ wbf,
    const float* __restrict__ w, const float* __restrict__ winv,
    const int* __restrict__ labels,
    float* __restrict__ pl, float* __restrict__ tsv) {
    __shared__ ushort Als[BM * LDSTR];  // 20480 B
    __shared__ ushort Bls[BN * LDSTR];  // 10240 B
    __shared__ float psum[2][BM];       // 2048 B

    const int tid = threadIdx.x;
    const int rowBase = blockIdx.x * BM;
    const int colBase = blockIdx.y * BN;
    const int lane = tid & 63, wv = tid >> 6;
    const int wave_m = wv & 3, wave_n = wv >> 2;
    const int lr = lane & 15, quad = lane >> 4;

    // staging indices
    const int arow = tid >> 1, ahalf = tid & 1; // A: 256 rows x 2 halves (16B each)
    const int bcol = tid >> 2, bq = tid & 3;    // B: 128 rows x 4 quarters
    const int bcls = colBase + bcol;
    const bool bvalid = bcls < NCLS;

    floatx4 acc[4][4];
#pragma unroll
    for (int i = 0; i < 4; i++)
#pragma unroll
        for (int j = 0; j < 4; j++) acc[i][j] = (floatx4){0.f, 0.f, 0.f, 0.f};

    for (int kt = 0; kt < EMB; kt += BK) {
        // stage A (bf16 copy): 32 B per thread
        {
            const ushort* src = nebf + (size_t)(rowBase + arow) * EMB + kt + ahalf * 16;
            uint4 v0 = *(const uint4*)(src);
            uint4 v1 = *(const uint4*)(src + 8);
            ushort* dst = &Als[arow * LDSTR + ahalf * 16];
            *(uint4*)(dst) = v0;
            *(uint4*)(dst + 8) = v1;
        }
        // stage B: 16 B per thread (PRE: bf16 copy; else fp32 load + convert)
        if (PRE) {
            uint4 v = make_uint4(0u, 0u, 0u, 0u);
            if (bvalid) v = *(const uint4*)(wbf + (size_t)bcls * EMB + kt + bq * 8);
            *(uint4*)&Bls[bcol * LDSTR + bq * 8] = v;
        } else {
            float4 v0 = make_float4(0.f, 0.f, 0.f, 0.f);
            float4 v1 = make_float4(0.f, 0.f, 0.f, 0.f);
            if (bvalid) {
                const float* src = w + (size_t)bcls * EMB + kt + bq * 8;
                v0 = *(const float4*)(src);
                v1 = *(const float4*)(src + 4);
            }
            union { ushort us[8]; uint4 v; } pk;
            pk.us[0] = f2bf(v0.x); pk.us[1] = f2bf(v0.y);
            pk.us[2] = f2bf(v0.z); pk.us[3] = f2bf(v0.w);
            pk.us[4] = f2bf(v1.x); pk.us[5] = f2bf(v1.y);
            pk.us[6] = f2bf(v1.z); pk.us[7] = f2bf(v1.w);
            *(uint4*)&Bls[bcol * LDSTR + bq * 8] = pk.v;
        }
        __syncthreads();

        bf16x8 af[4], bfr[4];
#pragma unroll
        for (int i = 0; i < 4; i++)
            af[i] = *(const bf16x8*)&Als[(wave_m * 64 + i * 16 + lr) * LDSTR + quad * 8];
#pragma unroll
        for (int j = 0; j < 4; j++)
            bfr[j] = *(const bf16x8*)&Bls[(wave_n * 64 + j * 16 + lr) * LDSTR + quad * 8];
#pragma unroll
        for (int i = 0; i < 4; i++)
#pragma unroll
            for (int j = 0; j < 4; j++)
                acc[i][j] = __builtin_amdgcn_mfma_f32_16x16x32_bf16(af[i], bfr[j], acc[i][j], 0, 0, 0);
        __syncthreads();
    }

    // ---- epilogue: contribution = exp(64*cos - 64); max statically = 64 ----
    float wvv[4];
    if (!PRE) {
#pragma unroll
        for (int j = 0; j < 4; j++) {
            int gc = colBase + wave_n * 64 + j * 16 + lr;
            wvv[j] = (gc < NCLS) ? winv[gc] : 0.f;
        }
    }
#pragma unroll
    for (int i = 0; i < 4; i++) {
#pragma unroll
        for (int r = 0; r < 4; r++) {
            int rowloc = wave_m * 64 + i * 16 + quad * 4 + r;
            int grow = rowBase + rowloc;
            int lbl = labels[grow];
            float s = 0.f;
#pragma unroll
            for (int j = 0; j < 4; j++) {
                int gc = colBase + wave_n * 64 + j * 16 + lr;
                if (gc < NCLS) {
                    float c = PRE ? acc[i][j][r] : acc[i][j][r] * wvv[j];
                    c = fminf(fmaxf(c, -1.f), 1.f);
                    if (gc == lbl) {
                        float tt = fminf(fmaxf(c, -1.f + EPSS), 1.f - EPSS);
                        c = __cosf(acosf(tt) + MARGIN2);
                        tsv[grow] = c * S_SCALE; // unique writer across grid
                    }
                    s += expf(c * S_SCALE - S_SCALE);
                }
            }
#pragma unroll
            for (int m = 1; m < 16; m <<= 1) s += __shfl_xor(s, m);
            if (lr == 0) psum[wave_n][rowloc] = s;
        }
    }
    __syncthreads();
    if (tid < BM) {
        size_t grow = rowBase + tid;
        pl[grow * NCHUNKS + blockIdx.y] = psum[0][tid] + psum[1][tid];
    }
}

// Kernel 4: per-row sum over chunk partials -> row loss (max fixed at 64).
__global__ void chunk_reduce_kernel(const float* __restrict__ pl,
                                    const float* __restrict__ tsv, float* __restrict__ rowloss) {
    int r = blockIdx.x, t = threadIdx.x;
    const float* l = pl + (size_t)r * NCHUNKS;
    __shared__ float red[256];
    float s = 0.f;
    for (int i = t; i < NCHUNKS; i += 256) s += l[i];
    red[t] = s;
    __syncthreads();
    for (int o = 128; o > 0; o >>= 1) {
        if (t < o) red[t] += red[t + o];
        __syncthreads();
    }
    if (t == 0) rowloss[r] = S_SCALE + logf(red[0]) - tsv[r];
}

// Kernel 5: mean over rows -> scalar loss.
__global__ void final_kernel(const float* __restrict__ rowloss, float* __restrict__ out) {
    int t = threadIdx.x;
    float s = 0.f;
    for (int i = t; i < BATCH; i += 256) s += rowloss[i];
    __shared__ float red[256];
    red[t] = s;
    __syncthreads();
    for (int o = 128; o > 0; o >>= 1) {
        if (t < o) red[t] += red[t + o];
        __syncthreads();
    }
    if (t == 0) out[0] = red[0] / (float)BATCH;
}

extern "C" void kernel_launch(void* const* d_in, const int* in_sizes, int n_in,
                              void* d_out, int out_size, void* d_ws, size_t ws_size,
                              hipStream_t stream) {
    const float* emb = (const float*)d_in[0];
    const float* w = (const float*)d_in[1];
    const int* labels = (const int*)d_in[2];
    float* ws = (float*)d_ws;
    ushort* nebf = (ushort*)(ws + OFF_NEBF);
    float* winv = ws + OFF_WINV;
    float* pl = ws + OFF_PL;
    float* tsv = ws + OFF_TSV;
    float* rl = ws + OFF_RL;
    ushort* wbf = (ushort*)(ws + OFF_WBF);

    const bool pre = ws_size >= NEED_BYTES;

    norm_emb_kernel<<<BATCH, 256, 0, stream>>>(emb, nebf);
    dim3 grid(BATCH / BM, NCHUNKS); // x = row-group (fast) for W reuse in L2/L3
    if (pre) {
        norm_w_kernel<<<NCLS / 4, 256, 0, stream>>>(w, wbf);
        gemm_lse_kernel<true><<<grid, 512, 0, stream>>>(nebf, wbf, w, winv, labels, pl, tsv);
    } else {
        winv_kernel<<<NCLS / 4, 256, 0, stream>>>(w, winv);
        gemm_lse_kernel<false><<<grid, 512, 0, stream>>>(nebf, wbf, w, winv, labels, pl, tsv);
    }
    chunk_reduce_kernel<<<BATCH, 256, 0, stream>>>(pl, tsv, rl);
    final_kernel<<<1, 256, 0, stream>>>(rl, (float*)d_out);
}

// Round 4
// 894.805 us; speedup vs baseline: 8.1591x; 1.0681x over previous
//
#include <hip/hip_runtime.h>
#include <math.h>

// ArcFace margin loss: B=1024 x E=512 embeddings vs C=200000 x E weight.
// Round 4: global_load_lds (width=16) staging for A and B tiles (m97-style),
// unpadded LDS layout (64 B row stride - exact bank tiling for ds_read_b128),
// __expf epilogue. PRE path = pre-normalized bf16 W; fallback converts in-kernel.

#define S_SCALE 64.0f
#define MARGIN2 0.5f
#define EPSS 1e-7f

#define BATCH 1024
#define EMB 512
#define NCLS 200000

#define BM 256
#define BN 128
#define BK 32
#define NCHUNKS ((NCLS + BN - 1) / BN) // 1563
#define NCLS_PAD (NCHUNKS * BN)        // 200064

typedef __bf16 bf16x8 __attribute__((ext_vector_type(8)));
typedef float floatx4 __attribute__((ext_vector_type(4)));

// ---- workspace layout (float offsets) ----
#define OFF_NEBF 0
#define LEN_NEBF (BATCH * EMB / 2)           // 262144 floats
#define OFF_WINV (OFF_NEBF + LEN_NEBF)       // fallback path only
#define LEN_WINV 200192
#define OFF_PL (OFF_WINV + LEN_WINV)
#define LEN_P (BATCH * NCHUNKS)              // 1600512
#define OFF_TSV (OFF_PL + LEN_P)
#define OFF_RL (OFF_TSV + BATCH)
#define OFF_WBF (OFF_RL + BATCH)             // ~8.3 MB so far
#define LEN_WBF ((size_t)NCLS_PAD * EMB / 2) // ~205 MB
#define NEED_BYTES (((size_t)OFF_WBF + LEN_WBF) * 4)

__device__ inline ushort f2bf(float f) {
    unsigned u = __float_as_uint(f);
    unsigned r = (u + 0x7FFFu + ((u >> 16) & 1u)) >> 16; // RNE
    return (ushort)r;
}

// async global->LDS, 16 B per lane; LDS dest = wave-uniform base + lane*16.
__device__ __forceinline__ void gload_lds16(const void* g, void* l) {
    __builtin_amdgcn_global_load_lds(
        (const __attribute__((address_space(1))) void*)g,
        (__attribute__((address_space(3))) void*)l, 16, 0, 0);
}

// Kernel 1: L2-normalize embedding rows -> bf16. One block per row.
__global__ void norm_emb_kernel(const float* __restrict__ e, ushort* __restrict__ nebf) {
    int r = blockIdx.x;
    int t = threadIdx.x;
    float v0 = e[r * EMB + t];
    float v1 = e[r * EMB + t + 256];
    __shared__ float red[256];
    red[t] = v0 * v0 + v1 * v1;
    __syncthreads();
    for (int o = 128; o > 0; o >>= 1) {
        if (t < o) red[t] += red[t + o];
        __syncthreads();
    }
    float inv = 1.0f / fmaxf(sqrtf(red[0]), 1e-12f);
    nebf[r * EMB + t] = f2bf(v0 * inv);
    nebf[r * EMB + t + 256] = f2bf(v1 * inv);
}

// Kernel 2a (PRE path): per-class normalize + fp32->bf16 convert, one wave/row.
__global__ void norm_w_kernel(const float* __restrict__ w, ushort* __restrict__ wbf) {
    int tid = threadIdx.x;
    int wv = tid >> 6, lane = tid & 63;
    int row = blockIdx.x * 4 + wv; // grid = 50000 -> exactly 200000 rows
    const float* wr = w + (size_t)row * EMB;
    float4 v0 = *(const float4*)(wr + lane * 4);
    float4 v1 = *(const float4*)(wr + lane * 4 + 256);
    float ss = v0.x * v0.x + v0.y * v0.y + v0.z * v0.z + v0.w * v0.w
             + v1.x * v1.x + v1.y * v1.y + v1.z * v1.z + v1.w * v1.w;
#pragma unroll
    for (int m = 32; m >= 1; m >>= 1) ss += __shfl_xor(ss, m);
    float inv = 1.0f / fmaxf(sqrtf(ss), 1e-12f);
    ushort* dst = wbf + (size_t)row * EMB;
    ushort4 p0, p1;
    p0.x = f2bf(v0.x * inv); p0.y = f2bf(v0.y * inv);
    p0.z = f2bf(v0.z * inv); p0.w = f2bf(v0.w * inv);
    p1.x = f2bf(v1.x * inv); p1.y = f2bf(v1.y * inv);
    p1.z = f2bf(v1.z * inv); p1.w = f2bf(v1.w * inv);
    *(ushort4*)(dst + lane * 4) = p0;
    *(ushort4*)(dst + lane * 4 + 256) = p1;
}

// Kernel 2b (fallback): per-class inverse norms only.
__global__ void winv_kernel(const float* __restrict__ w, float* __restrict__ winv) {
    int tid = threadIdx.x;
    int wv = tid >> 6, lane = tid & 63;
    int row = blockIdx.x * 4 + wv;
    const float* wr = w + (size_t)row * EMB;
    float ss = 0.f;
#pragma unroll
    for (int q = 0; q < 8; ++q) {
        float v = wr[lane + 64 * q];
        ss += v * v;
    }
#pragma unroll
    for (int m = 32; m >= 1; m >>= 1) ss += __shfl_xor(ss, m);
    if (lane == 0) winv[row] = 1.0f / fmaxf(sqrtf(ss), 1e-12f);
}

// Kernel 3: bf16 MFMA GEMM + fused arcface epilogue (fixed max = 64).
// Block = 512 threads = 8 waves (wave_m 0..3, wave_n 0..1), each wave 64x64.
// LDS tiles unpadded: row stride 32 bf16 = 64 B (required by global_load_lds).
template <bool PRE>
__global__ __launch_bounds__(512) void gemm_lse_kernel(
    const ushort* __restrict__ nebf, const ushort* __restrict__ wbf,
    const float* __restrict__ w, const float* __restrict__ winv,
    const int* __restrict__ labels,
    float* __restrict__ pl, float* __restrict__ tsv) {
    __shared__ ushort Als[BM * 32];  // 16 KB
    __shared__ ushort Bls[BN * 32];  // 8 KB
    __shared__ float psum[2][BM];    // 2 KB

    const int tid = threadIdx.x;
    const int rowBase = blockIdx.x * BM;
    const int colBase = blockIdx.y * BN;
    const int lane = tid & 63, wv = tid >> 6;
    const int wave_m = wv & 3, wave_n = wv >> 2;
    const int lr = lane & 15, quad = lane >> 4;

    // staging lane mapping: 1 KB segment = 16 rows x 64 B; lane l -> row l/4, koff (l&3)*8
    const int srow = lane >> 2, skoff = (lane & 3) * 8;
    // fallback manual B staging indices
    const int bcol = tid >> 2, bq = tid & 3;
    const int bcls = colBase + bcol;
    const bool bvalid = bcls < NCLS;

    floatx4 acc[4][4];
#pragma unroll
    for (int i = 0; i < 4; i++)
#pragma unroll
        for (int j = 0; j < 4; j++) acc[i][j] = (floatx4){0.f, 0.f, 0.f, 0.f};

    // per-wave staging source pointers (advance by BK each K-step)
    const ushort* aseg0 = nebf + (size_t)(rowBase + wv * 32 + srow) * EMB + skoff;
    const ushort* aseg1 = aseg0 + (size_t)16 * EMB;
    const ushort* bseg = PRE ? (wbf + (size_t)(colBase + wv * 16 + srow) * EMB + skoff) : (const ushort*)0;
    ushort* albase0 = &Als[(wv * 32) * 32];
    ushort* albase1 = &Als[(wv * 32 + 16) * 32];
    ushort* blbase = &Bls[(wv * 16) * 32];

    for (int kt = 0; kt < EMB; kt += BK) {
        gload_lds16(aseg0 + kt, albase0);
        gload_lds16(aseg1 + kt, albase1);
        if (PRE) {
            gload_lds16(bseg + kt, blbase);
        } else {
            float4 v0 = make_float4(0.f, 0.f, 0.f, 0.f);
            float4 v1 = make_float4(0.f, 0.f, 0.f, 0.f);
            if (bvalid) {
                const float* src = w + (size_t)bcls * EMB + kt + bq * 8;
                v0 = *(const float4*)(src);
                v1 = *(const float4*)(src + 4);
            }
            union { ushort us[8]; uint4 v; } pk;
            pk.us[0] = f2bf(v0.x); pk.us[1] = f2bf(v0.y);
            pk.us[2] = f2bf(v0.z); pk.us[3] = f2bf(v0.w);
            pk.us[4] = f2bf(v1.x); pk.us[5] = f2bf(v1.y);
            pk.us[6] = f2bf(v1.z); pk.us[7] = f2bf(v1.w);
            *(uint4*)&Bls[bcol * 32 + bq * 8] = pk.v;
        }
        __syncthreads();

        bf16x8 af[4], bfr[4];
#pragma unroll
        for (int i = 0; i < 4; i++)
            af[i] = *(const bf16x8*)&Als[(wave_m * 64 + i * 16 + lr) * 32 + quad * 8];
#pragma unroll
        for (int j = 0; j < 4; j++)
            bfr[j] = *(const bf16x8*)&Bls[(wave_n * 64 + j * 16 + lr) * 32 + quad * 8];
#pragma unroll
        for (int i = 0; i < 4; i++)
#pragma unroll
            for (int j = 0; j < 4; j++)
                acc[i][j] = __builtin_amdgcn_mfma_f32_16x16x32_bf16(af[i], bfr[j], acc[i][j], 0, 0, 0);
        __syncthreads();
    }

    // ---- epilogue: contribution = exp(64*cos - 64); max statically = 64 ----
    float wvv[4];
    if (!PRE) {
#pragma unroll
        for (int j = 0; j < 4; j++) {
            int gc = colBase + wave_n * 64 + j * 16 + lr;
            wvv[j] = (gc < NCLS) ? winv[gc] : 0.f;
        }
    }
#pragma unroll
    for (int i = 0; i < 4; i++) {
#pragma unroll
        for (int r = 0; r < 4; r++) {
            int rowloc = wave_m * 64 + i * 16 + quad * 4 + r;
            int grow = rowBase + rowloc;
            int lbl = labels[grow];
            float s = 0.f;
#pragma unroll
            for (int j = 0; j < 4; j++) {
                int gc = colBase + wave_n * 64 + j * 16 + lr;
                if (gc < NCLS) {
                    float c = PRE ? acc[i][j][r] : acc[i][j][r] * wvv[j];
                    c = fminf(fmaxf(c, -1.f), 1.f);
                    if (gc == lbl) {
                        float tt = fminf(fmaxf(c, -1.f + EPSS), 1.f - EPSS);
                        c = __cosf(acosf(tt) + MARGIN2);
                        tsv[grow] = c * S_SCALE; // unique writer across grid
                    }
                    s += __expf(c * S_SCALE - S_SCALE);
                }
            }
#pragma unroll
            for (int m = 1; m < 16; m <<= 1) s += __shfl_xor(s, m);
            if (lr == 0) psum[wave_n][rowloc] = s;
        }
    }
    __syncthreads();
    if (tid < BM) {
        size_t grow = rowBase + tid;
        pl[grow * NCHUNKS + blockIdx.y] = psum[0][tid] + psum[1][tid];
    }
}

// Kernel 4: per-row sum over chunk partials -> row loss (max fixed at 64).
__global__ void chunk_reduce_kernel(const float* __restrict__ pl,
                                    const float* __restrict__ tsv, float* __restrict__ rowloss) {
    int r = blockIdx.x, t = threadIdx.x;
    const float* l = pl + (size_t)r * NCHUNKS;
    __shared__ float red[256];
    float s = 0.f;
    for (int i = t; i < NCHUNKS; i += 256) s += l[i];
    red[t] = s;
    __syncthreads();
    for (int o = 128; o > 0; o >>= 1) {
        if (t < o) red[t] += red[t + o];
        __syncthreads();
    }
    if (t == 0) rowloss[r] = S_SCALE + logf(red[0]) - tsv[r];
}

// Kernel 5: mean over rows -> scalar loss.
__global__ void final_kernel(const float* __restrict__ rowloss, float* __restrict__ out) {
    int t = threadIdx.x;
    float s = 0.f;
    for (int i = t; i < BATCH; i += 256) s += rowloss[i];
    __shared__ float red[256];
    red[t] = s;
    __syncthreads();
    for (int o = 128; o > 0; o >>= 1) {
        if (t < o) red[t] += red[t + o];
        __syncthreads();
    }
    if (t == 0) out[0] = red[0] / (float)BATCH;
}

extern "C" void kernel_launch(void* const* d_in, const int* in_sizes, int n_in,
                              void* d_out, int out_size, void* d_ws, size_t ws_size,
                              hipStream_t stream) {
    const float* emb = (const float*)d_in[0];
    const float* w = (const float*)d_in[1];
    const int* labels = (const int*)d_in[2];
    float* ws = (float*)d_ws;
    ushort* nebf = (ushort*)(ws + OFF_NEBF);
    float* winv = ws + OFF_WINV;
    float* pl = ws + OFF_PL;
    float* tsv = ws + OFF_TSV;
    float* rl = ws + OFF_RL;
    ushort* wbf = (ushort*)(ws + OFF_WBF);

    const bool pre = ws_size >= NEED_BYTES;

    norm_emb_kernel<<<BATCH, 256, 0, stream>>>(emb, nebf);
    dim3 grid(BATCH / BM, NCHUNKS); // x = row-group (fast) for W reuse in L2/L3
    if (pre) {
        norm_w_kernel<<<NCLS / 4, 256, 0, stream>>>(w, wbf);
        gemm_lse_kernel<true><<<grid, 512, 0, stream>>>(nebf, wbf, w, winv, labels, pl, tsv);
    } else {
        winv_kernel<<<NCLS / 4, 256, 0, stream>>>(w, winv);
        gemm_lse_kernel<false><<<grid, 512, 0, stream>>>(nebf, wbf, w, winv, labels, pl, tsv);
    }
    chunk_reduce_kernel<<<BATCH, 256, 0, stream>>>(pl, tsv, rl);
    final_kernel<<<1, 256, 0, stream>>>(rl, (float*)d_out);
}